// Round 14
// baseline (335.775 us; speedup 1.0000x reference)
//
// VQ layer (gumbel-softmax VQ) fused pipeline for MI355X (gfx950). Round 14.
//
//   K0a split_w : W_h, W_logits (512x512 f32) -> f16 hi/lo planes in ws (2 MB)
//   K0b split_x : X (65536x512 f32) -> f16 hi/lo planes IN THE LOGITS REGION
//                 of d_out (134 MB, dead until K2 overwrites it)
//   K1  gemm4<0,0>: hiddens = relu(X @ Wh^T + bh) -> f16 hi/lo planes in the
//                 codes region of d_out (dead until K3 overwrites it)
//   K2  gemm4<0,1>: logits = hiddens @ Wl^T + bl -> logits region (OVERWRITES
//                 the dead X planes -> their dirty L3 lines are rewritten,
//                 never wasted on writeback)
//   K3  argmax  : z = logits + gumbel(u); codes[row,:] = codebook[argmax z,:]
//                 (overwrites the dead H planes)
//
// Round-13 lesson: producer-split gemm5 plateaued at ~177us across three
// scheduling/swizzle variants (MfmaUtil 25%, unexplained VALU+stall ~2/3 of
// step time) — abandoned. Round-7 lesson revisited: the split_x pipeline's
// overhead was NOT split_x itself but 134 MB of dirty never-re-read X-plane
// lines in ws stealing writeback BW under K2/K3. This round relocates the X
// planes into d_out where K2's logits stores overwrite them while dirty.
// Round-6 lesson: latency-chain work (logf/shfl) stays OUT of 2-block/CU
// GEMMs. Round-5 lesson: consumer-side split is 3x slower than presplit.
//
// f32-GEMM emulation: a = hi + lo*2^-12 (f16 split, lo scaled by 2^12), using
// 3 MFMAs: hi.hi -> acc_hh ; hi.lo + lo.hi -> acc_mx ; D = acc_hh + acc_mx*2^-12.
//
// GEMM shell (proven R5/R7/R10): 128x128 tile, 4 waves, 4x4 of 16x16x32 f16
// MFMA, BK=32, double-buffered LDS (2x32KB, 2 blocks/CU), counted
// s_waitcnt vmcnt(8) + raw s_barrier (prefetch in flight across barriers),
// XOR-swizzled global_load_lds source (rule 21), XCD-chunked block swizzle.

#include <hip/hip_runtime.h>
#include <hip/hip_fp16.h>

typedef _Float16 h16;
typedef __attribute__((ext_vector_type(8))) _Float16 h16x8;
typedef __attribute__((ext_vector_type(4))) _Float16 h16x4;
typedef __attribute__((ext_vector_type(4))) float f32x4;

#define KDIM 512
#define NDIM 512
#define LO_SCALE 4096.0f
#define LO_INV   0.000244140625f

__device__ __forceinline__ void gload16(const void* g, void* l) {
  __builtin_amdgcn_global_load_lds((const __attribute__((address_space(1))) void*)g,
                                   (__attribute__((address_space(3))) void*)l, 16, 0, 0);
}

#define WAITV(n) asm volatile("s_waitcnt vmcnt(" #n ")" ::: "memory")
#define WAITL0() asm volatile("s_waitcnt lgkmcnt(0)" ::: "memory")
#define SB() __builtin_amdgcn_sched_barrier(0)

// ---------------- K0a: split weights into f16 hi/lo planes ----------------
__global__ void split_w(const float* __restrict__ Wh, const float* __restrict__ Wl,
                        h16* __restrict__ WhHi, h16* __restrict__ WhLo,
                        h16* __restrict__ WlHi, h16* __restrict__ WlLo) {
  int i = blockIdx.x * 256 + threadIdx.x;          // 262144 elements
  float a = Wh[i];
  h16 h = (h16)a;
  WhHi[i] = h; WhLo[i] = (h16)((a - (float)h) * LO_SCALE);
  a = Wl[i];
  h = (h16)a;
  WlHi[i] = h; WlLo[i] = (h16)((a - (float)h) * LO_SCALE);
}

// ---------------- K0b: split inputs into f16 hi/lo planes ----------------
__global__ void split_x(const f32x4* __restrict__ X, h16x4* __restrict__ XHi,
                        h16x4* __restrict__ XLo) {
  int i = blockIdx.x * 256 + threadIdx.x;          // 8388608 f32x4 groups
  f32x4 a = X[i];
  h16x4 hv, lv;
#pragma unroll
  for (int j = 0; j < 4; ++j) {
    h16 h = (h16)a[j];
    hv[j] = h;
    lv[j] = (h16)((a[j] - (float)h) * LO_SCALE);
  }
  XHi[i] = hv; XLo[i] = lv;
}

// ====== GEMM: C[m,n] = sum_k A[m,k]*B[n,k] (+bias, epilogue); A presplit ======
// EPI 0: relu + split -> OHi/OLo planes.  EPI 1: f32 -> Cf32.
// Both epilogues repack through LDS for fully-coalesced 16B/lane stores.
template <int EPI>
__launch_bounds__(256, 2)
__global__ void gemm4_k(const h16* __restrict__ AHi, const h16* __restrict__ ALo,
                        const h16* __restrict__ BHi, const h16* __restrict__ BLo,
                        const float* __restrict__ bias,
                        float* __restrict__ Cf32,
                        h16* __restrict__ OHi, h16* __restrict__ OLo) {
  __shared__ __align__(16) char lds[65536];
  const int tid = threadIdx.x;
  const int wave = tid >> 6, lane = tid & 63;
  const int wg = (blockIdx.x & 7) * 256 + (blockIdx.x >> 3);
  const int bm = wg >> 2, bn = wg & 3;
  const int wm = wave >> 1, wn = wave & 1;
  const long arow0 = (long)bm * 128;
  const int brow0 = bn * 128;
  const int q = lane >> 4, rlo = lane & 15;

  f32x4 acc_hh[4][4] = {};
  f32x4 acc_mx[4][4] = {};

#define STAGE4(bufoff, kt)                                                    \
  {                                                                           \
    _Pragma("unroll")                                                         \
    for (int pass = 0; pass < 4; ++pass) {                                    \
      int p = pass * 4096 + wave * 1024 + lane * 16;                          \
      int row = p >> 7;                                                       \
      int gs = ((p >> 4) & 7) ^ (row & 7);                                    \
      const char* sp = (gs & 4) ? (const char*)ALo : (const char*)AHi;        \
      long off = (arow0 + row) * 1024 + (kt) * 64 + (gs & 3) * 16;            \
      gload16(sp + off, lds + (bufoff) + pass * 4096 + wave * 1024);          \
    }                                                                         \
    _Pragma("unroll")                                                         \
    for (int pass = 0; pass < 4; ++pass) {                                    \
      int p = pass * 4096 + wave * 1024 + lane * 16;                          \
      int row = p >> 7;                                                       \
      int gs = ((p >> 4) & 7) ^ (row & 7);                                    \
      const char* sp = (gs & 4) ? (const char*)BLo : (const char*)BHi;        \
      long off = (long)(brow0 + row) * 1024 + (kt) * 64 + (gs & 3) * 16;      \
      gload16(sp + off, lds + (bufoff) + 16384 + pass * 4096 + wave * 1024);  \
    }                                                                         \
  }

  STAGE4(0, 0);
  STAGE4(32768, 1);

#pragma unroll
  for (int t = 0; t < 16; ++t) {
    if (t < 15) { WAITV(8); } else { WAITV(0); }
    SB();
    __builtin_amdgcn_s_barrier();
    SB();

    const char* buf = lds + (t & 1) * 32768;
    h16x8 ah[4], al[4], bh[4], bl[4];
#pragma unroll
    for (int i = 0; i < 4; ++i) {
      int row = wm * 64 + i * 16 + rlo;
      int sw = (row & 7) << 4;
      ah[i] = *(const h16x8*)(buf + row * 128 + ((q * 16) ^ sw));
      al[i] = *(const h16x8*)(buf + row * 128 + ((q * 16 + 64) ^ sw));
      int rb = wn * 64 + i * 16 + rlo;
      int swb = (rb & 7) << 4;
      bh[i] = *(const h16x8*)(buf + 16384 + rb * 128 + ((q * 16) ^ swb));
      bl[i] = *(const h16x8*)(buf + 16384 + rb * 128 + ((q * 16 + 64) ^ swb));
    }
#pragma unroll
    for (int i = 0; i < 4; ++i)
#pragma unroll
      for (int j = 0; j < 4; ++j)
        acc_hh[i][j] = __builtin_amdgcn_mfma_f32_16x16x32_f16(ah[i], bh[j], acc_hh[i][j], 0, 0, 0);
#pragma unroll
    for (int i = 0; i < 4; ++i)
#pragma unroll
      for (int j = 0; j < 4; ++j)
        acc_mx[i][j] = __builtin_amdgcn_mfma_f32_16x16x32_f16(ah[i], bl[j], acc_mx[i][j], 0, 0, 0);
#pragma unroll
    for (int i = 0; i < 4; ++i)
#pragma unroll
      for (int j = 0; j < 4; ++j)
        acc_mx[i][j] = __builtin_amdgcn_mfma_f32_16x16x32_f16(al[i], bh[j], acc_mx[i][j], 0, 0, 0);

    WAITL0();
    SB();
    __builtin_amdgcn_s_barrier();
    SB();
    if (t + 2 < 16) STAGE4((t & 1) * 32768, t + 2);
  }
#undef STAGE4

  // C/D layout (16x16, m89): col=lane&15, row=(lane>>4)*4+r. Repack via LDS.
#pragma unroll
  for (int j = 0; j < 4; ++j) {
    int lcol = wn * 64 + j * 16 + rlo;
    float bv = bias[bn * 128 + lcol];
#pragma unroll
    for (int i = 0; i < 4; ++i)
#pragma unroll
      for (int r = 0; r < 4; ++r) {
        int lrow = wm * 64 + i * 16 + q * 4 + r;
        float v = acc_hh[i][j][r] + acc_mx[i][j][r] * LO_INV + bv;
        if (EPI == 0) {
          v = fmaxf(v, 0.0f);
          h16 h = (h16)v;
          h16 l = (h16)((v - (float)h) * LO_SCALE);
          unsigned uu = (unsigned)__builtin_bit_cast(unsigned short, h) |
                        ((unsigned)__builtin_bit_cast(unsigned short, l) << 16);
          *(unsigned*)(lds + lrow * 512 + lcol * 4) = uu;
        } else {
          *(float*)(lds + lrow * 512 + lcol * 4) = v;
        }
      }
  }
  __syncthreads();
#pragma unroll
  for (int pass = 0; pass < 16; ++pass) {
    int o = pass * 4096 + tid * 16;
    int lrow = o >> 9;
    int lcb = o & 511;
    if (EPI == 0) {
      uint4 d = *(const uint4*)(lds + o);
      uint2 hi, lo;
      hi.x = (d.x & 0xffffu) | (d.y << 16);
      hi.y = (d.z & 0xffffu) | (d.w << 16);
      lo.x = (d.x >> 16) | (d.y & 0xffff0000u);
      lo.y = (d.z >> 16) | (d.w & 0xffff0000u);
      long gb = (arow0 + lrow) * 1024 + bn * 256 + (lcb >> 1);
      *(uint2*)((char*)OHi + gb) = hi;
      *(uint2*)((char*)OLo + gb) = lo;
    } else {
      f32x4 d = *(const f32x4*)(lds + o);
      long gb = (arow0 + lrow) * 2048 + bn * 512 + lcb;
      *(f32x4*)((char*)Cf32 + gb) = d;
    }
  }
}

// ---------------- K3: gumbel + argmax + codebook gather ----------------
__global__ void k3_argmax_gather(const float* __restrict__ logits,
                                 const float* __restrict__ u,
                                 const float* __restrict__ cb,
                                 const int* __restrict__ testing,
                                 float* __restrict__ codes) {
  const int wave = threadIdx.x >> 6, lane = threadIdx.x & 63;
  const long row = (long)blockIdx.x * 4 + wave;    // one wave per row
  const f32x4* lrow = (const f32x4*)(logits + row * 512);
  const f32x4* urow = (const f32x4*)(u + row * 512);
  const int test = *testing;

  float best = -3.4e38f;
  int bi = 0;
#pragma unroll
  for (int h = 0; h < 2; ++h) {
    int c4 = h * 64 + lane;
    f32x4 z = lrow[c4];
    if (!test) {
      f32x4 uu = urow[c4];
#pragma unroll
      for (int t = 0; t < 4; ++t)
        z[t] += -logf(-logf(uu[t] + 1e-20f) + 1e-20f);
    }
#pragma unroll
    for (int t = 0; t < 4; ++t) {                  // in-lane ascending indices
      int c = c4 * 4 + t;
      if (z[t] > best) { best = z[t]; bi = c; }
    }
  }
#pragma unroll
  for (int off = 32; off; off >>= 1) {             // max with min-index ties
    float ob = __shfl_xor(best, off);
    int oi = __shfl_xor(bi, off);
    if (ob > best || (ob == best && oi < bi)) { best = ob; bi = oi; }
  }
  const f32x4* src = (const f32x4*)(cb + (long)bi * 512);
  f32x4* dst = (f32x4*)(codes + row * 512);
  dst[lane] = src[lane];
  dst[lane + 64] = src[lane + 64];
}

// ---------------- host ----------------
extern "C" void kernel_launch(void* const* d_in, const int* in_sizes, int n_in,
                              void* d_out, int out_size, void* d_ws, size_t ws_size,
                              hipStream_t stream) {
  const float* X = (const float*)d_in[0];
  const float* Wh = (const float*)d_in[1];
  const float* bh = (const float*)d_in[2];
  const float* Wl = (const float*)d_in[3];
  const float* bl = (const float*)d_in[4];
  const float* cb = (const float*)d_in[5];
  const float* u = (const float*)d_in[6];
  const int* testing = (const int*)d_in[7];

  float* logits = (float*)d_out;                   // 33554432 f32 (134 MB)
  float* codes = logits + 33554432;                // 33554432 f32 (134 MB)

  // Scratch-in-output lifetime chain (each region dead before overwritten):
  //   X planes  live in logits region: written K0b, read K1, KILLED by K2.
  //   H planes  live in codes  region: written K1, read K2, KILLED by K3.
  h16* Xhi = (h16*)logits;
  h16* Xlo = Xhi + 33554432;
  h16* Hhi = (h16*)codes;
  h16* Hlo = Hhi + 33554432;

  h16* WhHi = (h16*)d_ws;                          // 4 x 0.5 MB weight planes
  h16* WhLo = WhHi + 262144;
  h16* WlHi = WhLo + 262144;
  h16* WlLo = WlHi + 262144;

  split_w<<<dim3(1024), dim3(256), 0, stream>>>(Wh, Wl, WhHi, WhLo, WlHi, WlLo);

  split_x<<<dim3(32768), dim3(256), 0, stream>>>((const f32x4*)X, (h16x4*)Xhi, (h16x4*)Xlo);

  gemm4_k<0><<<dim3(2048), dim3(256), 0, stream>>>(Xhi, Xlo, WhHi, WhLo, bh,
                                                   nullptr, Hhi, Hlo);

  gemm4_k<1><<<dim3(2048), dim3(256), 0, stream>>>(Hhi, Hlo, WlHi, WlLo, bl,
                                                   logits, nullptr, nullptr);

  k3_argmax_gather<<<dim3(16384), dim3(256), 0, stream>>>(logits, u, cb, testing, codes);
}

// Round 15
// 318.217 us; speedup vs baseline: 1.0552x; 1.0552x over previous
//
// VQ layer (gumbel-softmax VQ) fused pipeline for MI355X (gfx950). Round 15.
//
//   K0  split_w : W_h, W_logits (512x512 f32) -> f16 hi/lo planes in ws (2 MB)
//   K1  gemm6   : hiddens = relu(X @ Wh^T + bh). FULL-N blocks: 64 M-rows x
//                 ALL 512 N-cols per block (1024 blocks, 8 waves). X tile
//                 (64x32 f32 = 8 KB) loaded 1 f32x4/thread, hi/lo-split
//                 in-reg, ds_written ONCE and consumed by all 8 waves /
//                 512 N-cols — conversion amortized 4x better than the
//                 N=128 tiles that plateaued at 175-215us across R5-R14.
//                 Output -> f16 hi/lo planes in codes region of d_out.
//   K2  gemm4<1>: logits = hiddens @ Wl^T + bl -> d_out (f32). PURE GEMM.
//   K3  argmax  : z = logits + gumbel(u); codes = codebook[argmax z] —
//                 standalone (R6 lesson); measured ~60us = 402 MB at
//                 6.7 TB/s = BW roofline, no further work.
//
// Cross-round algebra (R5/R7/R10/R13/R14): every GEMM1-feeding route cost
// ~175-215us (consumer-split 190, producer-split 177, split_x+presplit 215)
// vs presplit K2 = 55. Common factor: N=128 tiles amortize the f32->f16x2
// conversion over only 128 output cols. This round widens GEMM1 to N=512.
//
// f32-GEMM emulation: a = hi + lo*2^-12 (f16 split, lo scaled 2^12), 3 MFMAs:
// hi.hi -> acc_hh ; hi.lo + lo.hi -> acc_mx ; D = acc_hh + acc_mx*2^-12.
//
// gemm6 vmcnt ledger (units: aload=1 instr, bgld=8): steady top-of-t queue
// {B(t)x8, A(t+2), B(t+1)x8} = 17 -> WAITV(9) drains B(t). Compute issues
// A(t+3) -> stage queue {A(t+2), B(t+1)x8, A(t+3)} = 10 -> WAITV(9) drains
// A(t+2); awrite; bgld(t+2). Tails: t=13 stage WAITV(8) drains A15;
// t=14 top WAITV(8) drains B14; t=15 top WAITV(0).

#include <hip/hip_runtime.h>
#include <hip/hip_fp16.h>

typedef _Float16 h16;
typedef __attribute__((ext_vector_type(8))) _Float16 h16x8;
typedef __attribute__((ext_vector_type(4))) _Float16 h16x4;
typedef __attribute__((ext_vector_type(4))) float f32x4;

#define KDIM 512
#define NDIM 512
#define LO_SCALE 4096.0f
#define LO_INV   0.000244140625f

__device__ __forceinline__ void gload16(const void* g, void* l) {
  __builtin_amdgcn_global_load_lds((const __attribute__((address_space(1))) void*)g,
                                   (__attribute__((address_space(3))) void*)l, 16, 0, 0);
}

#define WAITV(n) asm volatile("s_waitcnt vmcnt(" #n ")" ::: "memory")
#define WAITL0() asm volatile("s_waitcnt lgkmcnt(0)" ::: "memory")
#define SB() __builtin_amdgcn_sched_barrier(0)

// ---------------- K0: split weights into f16 hi/lo planes ----------------
__global__ void split_w(const float* __restrict__ Wh, const float* __restrict__ Wl,
                        h16* __restrict__ WhHi, h16* __restrict__ WhLo,
                        h16* __restrict__ WlHi, h16* __restrict__ WlLo) {
  int i = blockIdx.x * 256 + threadIdx.x;          // 262144 elements
  float a = Wh[i];
  h16 h = (h16)a;
  WhHi[i] = h; WhLo[i] = (h16)((a - (float)h) * LO_SCALE);
  a = Wl[i];
  h = (h16)a;
  WlHi[i] = h; WlLo[i] = (h16)((a - (float)h) * LO_SCALE);
}

// ====== K1: gemm6 — H = relu(X @ Wh^T + bh), 64 x FULL-512 blocks ======
// LDS per buffer (72 KB): X planes [0,8K) = [64 rows][hi32|lo32] f16,
// swA(row) = ((row&1)<<6)|(((row>>1)&3)<<4); W planes [8K,72K) =
// [512 rows][hi32|lo32], swB(row) = (row&7)<<4 via pre-swizzled gload src.
// Double-buffered at 0 / 73728. Epilogue repack reuses [0,128K).
__launch_bounds__(512, 2)
__global__ void gemm6_k(const float* __restrict__ X,
                        const h16* __restrict__ BHi, const h16* __restrict__ BLo,
                        const float* __restrict__ bias,
                        h16* __restrict__ OHi, h16* __restrict__ OLo) {
  __shared__ __align__(16) char lds[147456];
  const int tid = threadIdx.x;
  const int wave = tid >> 6, lane = tid & 63;
  const int wn = wave;                             // 8 waves across N=512
  const long arow0 = (long)blockIdx.x * 64;
  const int q = lane >> 4, rlo = lane & 15;

  f32x4 acc_hh[4][4] = {};
  f32x4 acc_mx[4][4] = {};
  f32x4 areg[2];                                   // 2 in-flight X k-steps

  const int axrow = tid >> 3;                      // this thread's X-tile row
  const int ajb = (tid & 7) * 8;                   // byte pos of its 4 f16
  const int asw = ((axrow & 1) << 6) | (((axrow >> 1) & 3) << 4);

  auto aload = [&](f32x4& ar, int kt) {            // 8 KB: 1 f32x4/thread
    ar = *(const f32x4*)((const char*)X + (arow0 + axrow) * 2048 +
                         (long)kt * 128 + (tid & 7) * 16);
  };
  auto awrite = [&](const f32x4& ar, char* buf) {  // split + 2x ds_write_b64
    h16x4 hv, lv;
#pragma unroll
    for (int e = 0; e < 4; ++e) {
      h16 h = (h16)ar[e];
      hv[e] = h;
      lv[e] = (h16)((ar[e] - (float)h) * LO_SCALE);
    }
    *(h16x4*)(buf + axrow * 128 + (ajb ^ asw)) = hv;
    *(h16x4*)(buf + axrow * 128 + ((ajb + 64) ^ asw)) = lv;
  };
  auto bgld = [&](char* buf, int kt) {             // 64 KB: 8 gload16/thread
#pragma unroll
    for (int pass = 0; pass < 8; ++pass) {
      int p = pass * 8192 + wave * 1024 + lane * 16;
      int row = p >> 7;                            // 0..511
      int gs = ((p >> 4) & 7) ^ (row & 7);
      const char* sp = (gs & 4) ? (const char*)BLo : (const char*)BHi;
      long off = (long)row * 1024 + (long)kt * 64 + (gs & 3) * 16;
      gload16(sp + off, buf + 8192 + pass * 8192 + wave * 1024);
    }
  };

  // ---- prologue: steps 0,1 staged; A2 in flight ----
  aload(areg[0], 0);
  aload(areg[1], 1);
  WAITV(1);                                        // A0 landed
  awrite(areg[0], lds);
  bgld(lds, 0);                                    // {A1, B0x8}
  WAITV(8);                                        // A1 landed
  awrite(areg[1], lds + 73728);
  aload(areg[0], 2);                               // {B0x8, A2}
  bgld(lds + 73728, 1);                            // {B0x8, A2, B1x8} = 17
  WAITL0();                                        // ds_writes drained

#pragma unroll
  for (int t = 0; t < 16; ++t) {
    if (t <= 13) { WAITV(9); } else if (t == 14) { WAITV(8); } else { WAITV(0); }
    SB();
    __builtin_amdgcn_s_barrier();                  // buf[t&1] fully staged
    SB();

    if (t <= 12) aload(areg[(t + 3) & 1], t + 3);  // issue-early (T14)

    char* buf = lds + (t & 1) * 73728;
    h16x8 ah[4], al[4], bh[4], bl[4];
#pragma unroll
    for (int i = 0; i < 4; ++i) {
      int row = i * 16 + rlo;
      int swa = ((row & 1) << 6) | (((row >> 1) & 3) << 4);
      ah[i] = *(const h16x8*)(buf + row * 128 + ((q * 16) ^ swa));
      al[i] = *(const h16x8*)(buf + row * 128 + ((q * 16 + 64) ^ swa));
      int rb = wn * 64 + i * 16 + rlo;
      int swb = (rb & 7) << 4;
      bh[i] = *(const h16x8*)(buf + 8192 + rb * 128 + ((q * 16) ^ swb));
      bl[i] = *(const h16x8*)(buf + 8192 + rb * 128 + ((q * 16 + 64) ^ swb));
    }
#pragma unroll
    for (int i = 0; i < 4; ++i)
#pragma unroll
      for (int j = 0; j < 4; ++j)
        acc_hh[i][j] = __builtin_amdgcn_mfma_f32_16x16x32_f16(ah[i], bh[j], acc_hh[i][j], 0, 0, 0);
#pragma unroll
    for (int i = 0; i < 4; ++i)
#pragma unroll
      for (int j = 0; j < 4; ++j)
        acc_mx[i][j] = __builtin_amdgcn_mfma_f32_16x16x32_f16(ah[i], bl[j], acc_mx[i][j], 0, 0, 0);
#pragma unroll
    for (int i = 0; i < 4; ++i)
#pragma unroll
      for (int j = 0; j < 4; ++j)
        acc_mx[i][j] = __builtin_amdgcn_mfma_f32_16x16x32_f16(al[i], bh[j], acc_mx[i][j], 0, 0, 0);

    WAITL0();                                      // our ds_reads of buf done
    SB();
    __builtin_amdgcn_s_barrier();                  // all waves done with buf
    SB();
    if (t <= 12) {
      WAITV(9);                                    // A(t+2) landed
      awrite(areg[(t + 2) & 1], lds + (t & 1) * 73728);
      bgld(lds + (t & 1) * 73728, t + 2);
    } else if (t == 13) {
      WAITV(8);                                    // A15 landed (B14 flies)
      awrite(areg[1], lds + 73728);
      bgld(lds + 73728, 15);
    }
  }

  // ---- epilogue: relu+split -> u32 pack in LDS [64][512], coalesced out --
#pragma unroll
  for (int j = 0; j < 4; ++j) {
    int lcol = wn * 64 + j * 16 + rlo;
    float bv = bias[lcol];
#pragma unroll
    for (int i = 0; i < 4; ++i)
#pragma unroll
      for (int r = 0; r < 4; ++r) {
        int lrow = i * 16 + q * 4 + r;
        float v = fmaxf(acc_hh[i][j][r] + acc_mx[i][j][r] * LO_INV + bv, 0.0f);
        h16 h = (h16)v;
        h16 l = (h16)((v - (float)h) * LO_SCALE);
        unsigned uu = (unsigned)__builtin_bit_cast(unsigned short, h) |
                      ((unsigned)__builtin_bit_cast(unsigned short, l) << 16);
        *(unsigned*)(lds + lrow * 2048 + lcol * 4) = uu;
      }
  }
  __syncthreads();
#pragma unroll
  for (int pass = 0; pass < 16; ++pass) {
    int o = pass * 8192 + tid * 16;
    int lrow = o >> 11;                            // 2048-B packed rows
    int lcb = o & 2047;
    uint4 d = *(const uint4*)(lds + o);
    uint2 hi, lo;
    hi.x = (d.x & 0xffffu) | (d.y << 16);
    hi.y = (d.z & 0xffffu) | (d.w << 16);
    lo.x = (d.x >> 16) | (d.y & 0xffff0000u);
    lo.y = (d.z >> 16) | (d.w & 0xffff0000u);
    long gb = (arow0 + lrow) * 1024 + (lcb >> 1);
    *(uint2*)((char*)OHi + gb) = hi;
    *(uint2*)((char*)OLo + gb) = lo;
  }
}

// ====== K2: gemm4 (presplit planes) — logits, pure GEMM (proven ~55us) ======
template <int EPI>
__launch_bounds__(256, 2)
__global__ void gemm4_k(const h16* __restrict__ AHi, const h16* __restrict__ ALo,
                        const h16* __restrict__ BHi, const h16* __restrict__ BLo,
                        const float* __restrict__ bias,
                        float* __restrict__ Cf32,
                        h16* __restrict__ OHi, h16* __restrict__ OLo) {
  __shared__ __align__(16) char lds[65536];
  const int tid = threadIdx.x;
  const int wave = tid >> 6, lane = tid & 63;
  const int wg = (blockIdx.x & 7) * 256 + (blockIdx.x >> 3);
  const int bm = wg >> 2, bn = wg & 3;
  const int wm = wave >> 1, wn = wave & 1;
  const long arow0 = (long)bm * 128;
  const int brow0 = bn * 128;
  const int q = lane >> 4, rlo = lane & 15;

  f32x4 acc_hh[4][4] = {};
  f32x4 acc_mx[4][4] = {};

#define STAGE4(bufoff, kt)                                                    \
  {                                                                           \
    _Pragma("unroll")                                                         \
    for (int pass = 0; pass < 4; ++pass) {                                    \
      int p = pass * 4096 + wave * 1024 + lane * 16;                          \
      int row = p >> 7;                                                       \
      int gs = ((p >> 4) & 7) ^ (row & 7);                                    \
      const char* sp = (gs & 4) ? (const char*)ALo : (const char*)AHi;        \
      long off = (arow0 + row) * 1024 + (kt) * 64 + (gs & 3) * 16;            \
      gload16(sp + off, lds + (bufoff) + pass * 4096 + wave * 1024);          \
    }                                                                         \
    _Pragma("unroll")                                                         \
    for (int pass = 0; pass < 4; ++pass) {                                    \
      int p = pass * 4096 + wave * 1024 + lane * 16;                          \
      int row = p >> 7;                                                       \
      int gs = ((p >> 4) & 7) ^ (row & 7);                                    \
      const char* sp = (gs & 4) ? (const char*)BLo : (const char*)BHi;        \
      long off = (long)(brow0 + row) * 1024 + (kt) * 64 + (gs & 3) * 16;      \
      gload16(sp + off, lds + (bufoff) + 16384 + pass * 4096 + wave * 1024);  \
    }                                                                         \
  }

  STAGE4(0, 0);
  STAGE4(32768, 1);

#pragma unroll
  for (int t = 0; t < 16; ++t) {
    if (t < 15) { WAITV(8); } else { WAITV(0); }
    SB();
    __builtin_amdgcn_s_barrier();
    SB();

    const char* buf = lds + (t & 1) * 32768;
    h16x8 ah[4], al[4], bh[4], bl[4];
#pragma unroll
    for (int i = 0; i < 4; ++i) {
      int row = wm * 64 + i * 16 + rlo;
      int sw = (row & 7) << 4;
      ah[i] = *(const h16x8*)(buf + row * 128 + ((q * 16) ^ sw));
      al[i] = *(const h16x8*)(buf + row * 128 + ((q * 16 + 64) ^ sw));
      int rb = wn * 64 + i * 16 + rlo;
      int swb = (rb & 7) << 4;
      bh[i] = *(const h16x8*)(buf + 16384 + rb * 128 + ((q * 16) ^ swb));
      bl[i] = *(const h16x8*)(buf + 16384 + rb * 128 + ((q * 16 + 64) ^ swb));
    }
#pragma unroll
    for (int i = 0; i < 4; ++i)
#pragma unroll
      for (int j = 0; j < 4; ++j)
        acc_hh[i][j] = __builtin_amdgcn_mfma_f32_16x16x32_f16(ah[i], bh[j], acc_hh[i][j], 0, 0, 0);
#pragma unroll
    for (int i = 0; i < 4; ++i)
#pragma unroll
      for (int j = 0; j < 4; ++j)
        acc_mx[i][j] = __builtin_amdgcn_mfma_f32_16x16x32_f16(ah[i], bl[j], acc_mx[i][j], 0, 0, 0);
#pragma unroll
    for (int i = 0; i < 4; ++i)
#pragma unroll
      for (int j = 0; j < 4; ++j)
        acc_mx[i][j] = __builtin_amdgcn_mfma_f32_16x16x32_f16(al[i], bh[j], acc_mx[i][j], 0, 0, 0);

    WAITL0();
    SB();
    __builtin_amdgcn_s_barrier();
    SB();
    if (t + 2 < 16) STAGE4((t & 1) * 32768, t + 2);
  }
#undef STAGE4

#pragma unroll
  for (int j = 0; j < 4; ++j) {
    int lcol = wn * 64 + j * 16 + rlo;
    float bv = bias[bn * 128 + lcol];
#pragma unroll
    for (int i = 0; i < 4; ++i)
#pragma unroll
      for (int r = 0; r < 4; ++r) {
        int lrow = wm * 64 + i * 16 + q * 4 + r;
        float v = acc_hh[i][j][r] + acc_mx[i][j][r] * LO_INV + bv;
        if (EPI == 0) {
          v = fmaxf(v, 0.0f);
          h16 h = (h16)v;
          h16 l = (h16)((v - (float)h) * LO_SCALE);
          unsigned uu = (unsigned)__builtin_bit_cast(unsigned short, h) |
                        ((unsigned)__builtin_bit_cast(unsigned short, l) << 16);
          *(unsigned*)(lds + lrow * 512 + lcol * 4) = uu;
        } else {
          *(float*)(lds + lrow * 512 + lcol * 4) = v;
        }
      }
  }
  __syncthreads();
#pragma unroll
  for (int pass = 0; pass < 16; ++pass) {
    int o = pass * 4096 + tid * 16;
    int lrow = o >> 9;
    int lcb = o & 511;
    if (EPI == 0) {
      uint4 d = *(const uint4*)(lds + o);
      uint2 hi, lo;
      hi.x = (d.x & 0xffffu) | (d.y << 16);
      hi.y = (d.z & 0xffffu) | (d.w << 16);
      lo.x = (d.x >> 16) | (d.y & 0xffff0000u);
      lo.y = (d.z >> 16) | (d.w & 0xffff0000u);
      long gb = (arow0 + lrow) * 1024 + bn * 256 + (lcb >> 1);
      *(uint2*)((char*)OHi + gb) = hi;
      *(uint2*)((char*)OLo + gb) = lo;
    } else {
      f32x4 d = *(const f32x4*)(lds + o);
      long gb = (arow0 + lrow) * 2048 + bn * 512 + lcb;
      *(f32x4*)((char*)Cf32 + gb) = d;
    }
  }
}

// ---------------- K3: gumbel + argmax + codebook gather ----------------
__global__ void k3_argmax_gather(const float* __restrict__ logits,
                                 const float* __restrict__ u,
                                 const float* __restrict__ cb,
                                 const int* __restrict__ testing,
                                 float* __restrict__ codes) {
  const int wave = threadIdx.x >> 6, lane = threadIdx.x & 63;
  const long row = (long)blockIdx.x * 4 + wave;    // one wave per row
  const f32x4* lrow = (const f32x4*)(logits + row * 512);
  const f32x4* urow = (const f32x4*)(u + row * 512);
  const int test = *testing;

  float best = -3.4e38f;
  int bi = 0;
#pragma unroll
  for (int h = 0; h < 2; ++h) {
    int c4 = h * 64 + lane;
    f32x4 z = lrow[c4];
    if (!test) {
      f32x4 uu = urow[c4];
#pragma unroll
      for (int t = 0; t < 4; ++t)
        z[t] += -logf(-logf(uu[t] + 1e-20f) + 1e-20f);
    }
#pragma unroll
    for (int t = 0; t < 4; ++t) {                  // in-lane ascending indices
      int c = c4 * 4 + t;
      if (z[t] > best) { best = z[t]; bi = c; }
    }
  }
#pragma unroll
  for (int off = 32; off; off >>= 1) {             // max with min-index ties
    float ob = __shfl_xor(best, off);
    int oi = __shfl_xor(bi, off);
    if (ob > best || (ob == best && oi < bi)) { best = ob; bi = oi; }
  }
  const f32x4* src = (const f32x4*)(cb + (long)bi * 512);
  f32x4* dst = (f32x4*)(codes + row * 512);
  dst[lane] = src[lane];
  dst[lane + 64] = src[lane + 64];
}

// ---------------- host ----------------
extern "C" void kernel_launch(void* const* d_in, const int* in_sizes, int n_in,
                              void* d_out, int out_size, void* d_ws, size_t ws_size,
                              hipStream_t stream) {
  const float* X = (const float*)d_in[0];
  const float* Wh = (const float*)d_in[1];
  const float* bh = (const float*)d_in[2];
  const float* Wl = (const float*)d_in[3];
  const float* bl = (const float*)d_in[4];
  const float* cb = (const float*)d_in[5];
  const float* u = (const float*)d_in[6];
  const int* testing = (const int*)d_in[7];

  float* logits = (float*)d_out;                   // 33554432 f32
  float* codes = logits + 33554432;                // 33554432 f32
  // hiddens hi/lo f16 planes live in the codes region until K3 overwrites it
  h16* Hhi = (h16*)codes;
  h16* Hlo = Hhi + 33554432;

  h16* WhHi = (h16*)d_ws;                          // 4 x 0.5 MB weight planes
  h16* WhLo = WhHi + 262144;
  h16* WlHi = WhLo + 262144;
  h16* WlLo = WlHi + 262144;

  split_w<<<dim3(1024), dim3(256), 0, stream>>>(Wh, Wl, WhHi, WhLo, WlHi, WlLo);

  gemm6_k<<<dim3(1024), dim3(512), 0, stream>>>(X, WhHi, WhLo, bh, Hhi, Hlo);

  gemm4_k<1><<<dim3(2048), dim3(256), 0, stream>>>(Hhi, Hlo, WlHi, WlLo, bl,
                                                   logits, nullptr, nullptr);

  k3_argmax_gather<<<dim3(16384), dim3(256), 0, stream>>>(logits, u, cb, testing, codes);
}

// Round 16
// 311.605 us; speedup vs baseline: 1.0776x; 1.0212x over previous
//
// VQ layer (gumbel-softmax VQ) fused pipeline for MI355X (gfx950). Round 16.
//
//   K0  split_w : W_h, W_logits (512x512 f32) -> f16 hi/lo planes in ws (2 MB)
//   K1  gemm7   : hiddens = relu(X @ Wh^T + bh). 64M x 256N tiles, 4 waves,
//                 producer-split X (2 f32x4/thread -> in-reg f16 hi/lo ->
//                 2x ds_write_b128), B via global_load_lds from presplit
//                 planes. LDS 2x40KB = 80KB -> EXACTLY 2 blocks/CU: the
//                 other resident block overlaps this block's barrier drain.
//                 (R15 lesson: gemm6's 147KB LDS -> 1 block/CU -> zero
//                 overlap; all 2-barrier K1 variants sat at the m233-style
//                 ~600 TF cap. This is the last incremental variant — if it
//                 also lands >=160us, next round ports the 8-phase schedule.)
//   K2  gemm4<1>: logits = hiddens @ Wl^T + bl -> d_out (f32). PURE GEMM.
//   K3  argmax  : z = logits + gumbel(u); codes = codebook[argmax z].
//
// f32-GEMM emulation: a = hi + lo*2^-12 (f16 split, lo scaled 2^12), 3 MFMAs:
// hi.hi -> acc_hh ; hi.lo + lo.hi -> acc_mx ; D = acc_hh + acc_mx*2^-12.
//
// gemm7 vmcnt ledger (units: aload=2 instrs, bgld=8): steady top-of-t queue
// {B(t)x8, A(t+2)x2, B(t+1)x8} = 18 -> WAITV(10) drains B(t). Compute issues
// A(t+3)x2 -> stage queue {A(t+2)x2, B(t+1)x8, A(t+3)x2} = 12 -> WAITV(10)
// drains A(t+2); awrite; bgld(t+2) -> 18. Tails: t=13 stage WAITV(8) drains
// A15; t=14 top WAITV(8) drains B14; t=15 top WAITV(0) drains B15.

#include <hip/hip_runtime.h>
#include <hip/hip_fp16.h>

typedef _Float16 h16;
typedef __attribute__((ext_vector_type(8))) _Float16 h16x8;
typedef __attribute__((ext_vector_type(4))) _Float16 h16x4;
typedef __attribute__((ext_vector_type(4))) float f32x4;

#define KDIM 512
#define NDIM 512
#define LO_SCALE 4096.0f
#define LO_INV   0.000244140625f

__device__ __forceinline__ void gload16(const void* g, void* l) {
  __builtin_amdgcn_global_load_lds((const __attribute__((address_space(1))) void*)g,
                                   (__attribute__((address_space(3))) void*)l, 16, 0, 0);
}

#define WAITV(n) asm volatile("s_waitcnt vmcnt(" #n ")" ::: "memory")
#define WAITL0() asm volatile("s_waitcnt lgkmcnt(0)" ::: "memory")
#define SB() __builtin_amdgcn_sched_barrier(0)

// ---------------- K0: split weights into f16 hi/lo planes ----------------
__global__ void split_w(const float* __restrict__ Wh, const float* __restrict__ Wl,
                        h16* __restrict__ WhHi, h16* __restrict__ WhLo,
                        h16* __restrict__ WlHi, h16* __restrict__ WlLo) {
  int i = blockIdx.x * 256 + threadIdx.x;          // 262144 elements
  float a = Wh[i];
  h16 h = (h16)a;
  WhHi[i] = h; WhLo[i] = (h16)((a - (float)h) * LO_SCALE);
  a = Wl[i];
  h = (h16)a;
  WlHi[i] = h; WlLo[i] = (h16)((a - (float)h) * LO_SCALE);
}

// ====== K1: gemm7 — H = relu(X @ Wh^T + bh), 64M x 256N, 2 blocks/CU ======
// LDS per buffer (40 KB): A planes [0,8K) = [64 rows][hi64|lo64] f16 with
// swA(row) = ((row&1)<<6)|(((row>>1)&3)<<4); B planes [8K,40K) =
// [256 rows][hi64|lo64], swB(row) = (row&7)<<4 via pre-swizzled gload src.
// Buffers at 0 / 40960; epilogue repack reuses [0,64K). Total 80 KB.
__launch_bounds__(256, 2)
__global__ void gemm7_k(const float* __restrict__ X,
                        const h16* __restrict__ BHi, const h16* __restrict__ BLo,
                        const float* __restrict__ bias,
                        h16* __restrict__ OHi, h16* __restrict__ OLo) {
  __shared__ __align__(16) char lds[81920];
  const int tid = threadIdx.x;
  const int wave = tid >> 6, lane = tid & 63;
  const int wn = wave;                             // 4 waves across N=256
  const int wg = (blockIdx.x & 7) * 256 + (blockIdx.x >> 3);  // XCD-chunked
  const int bm = wg >> 1, bn = wg & 1;             // 1024 M-tiles x 2 N-halves
  const long arow0 = (long)bm * 64;
  const int brow0 = bn * 256;
  const int q = lane >> 4, rlo = lane & 15;

  f32x4 acc_hh[4][4] = {};
  f32x4 acc_mx[4][4] = {};
  f32x4 areg[2][2];                                // 2 in-flight X k-steps

  const int axrow = tid >> 2;                      // X-tile row (0..63)
  const int akb = (tid & 3) * 32;                  // 32-B chunk within 128-B k-row
  const int ajb = (tid & 3) * 16;                  // 16-B pos within 64-B plane half
  const int asw = ((axrow & 1) << 6) | (((axrow >> 1) & 3) << 4);

  auto aload = [&](f32x4 (&ar)[2], int kt) {       // 8 KB tile: 2 f32x4/thread
    const char* base = (const char*)X + (arow0 + axrow) * 2048 + (long)kt * 128 + akb;
    ar[0] = *(const f32x4*)base;
    ar[1] = *(const f32x4*)(base + 16);
  };
  auto awrite = [&](const f32x4 (&ar)[2], char* buf) {  // split + 2x ds_write_b128
    h16x8 hv, lv;
#pragma unroll
    for (int p = 0; p < 2; ++p)
#pragma unroll
      for (int e = 0; e < 4; ++e) {
        float a = ar[p][e];
        h16 h = (h16)a;
        hv[p * 4 + e] = h;
        lv[p * 4 + e] = (h16)((a - (float)h) * LO_SCALE);
      }
    *(h16x8*)(buf + axrow * 128 + (ajb ^ asw)) = hv;
    *(h16x8*)(buf + axrow * 128 + ((ajb + 64) ^ asw)) = lv;
  };
  auto bgld = [&](char* buf, int kt) {             // 32 KB: 8 gload16/thread
#pragma unroll
    for (int pass = 0; pass < 8; ++pass) {
      int p = pass * 4096 + tid * 16;
      int row = p >> 7;                            // 0..255
      int gs = ((p >> 4) & 7) ^ (row & 7);
      const char* sp = (gs & 4) ? (const char*)BLo : (const char*)BHi;
      long off = (long)(brow0 + row) * 1024 + (long)kt * 64 + (gs & 3) * 16;
      gload16(sp + off, buf + 8192 + pass * 4096 + wave * 1024);
    }
  };

  // ---- prologue: steps 0,1 staged; A2 in flight ----
  aload(areg[0], 0);
  aload(areg[1], 1);
  WAITV(2);                                        // A0 landed
  awrite(areg[0], lds);
  bgld(lds, 0);                                    // {A1x2, B0x8} = 10
  WAITV(8);                                        // A1 landed
  awrite(areg[1], lds + 40960);
  aload(areg[0], 2);                               // {B0x8, A2x2}
  bgld(lds + 40960, 1);                            // {B0x8, A2x2, B1x8} = 18
  WAITL0();                                        // ds_writes drained

#pragma unroll
  for (int t = 0; t < 16; ++t) {
    if (t <= 13) { WAITV(10); } else if (t == 14) { WAITV(8); } else { WAITV(0); }
    SB();
    __builtin_amdgcn_s_barrier();                  // buf[t&1] fully staged
    SB();

    if (t <= 12) aload(areg[(t + 3) & 1], t + 3);  // issue-early (T14)

    char* buf = lds + (t & 1) * 40960;
    h16x8 ah[4], al[4], bh[4], bl[4];
#pragma unroll
    for (int i = 0; i < 4; ++i) {
      int row = i * 16 + rlo;
      int swa = ((row & 1) << 6) | (((row >> 1) & 3) << 4);
      ah[i] = *(const h16x8*)(buf + row * 128 + ((q * 16) ^ swa));
      al[i] = *(const h16x8*)(buf + row * 128 + ((q * 16 + 64) ^ swa));
      int rb = wn * 64 + i * 16 + rlo;
      int swb = (rb & 7) << 4;
      bh[i] = *(const h16x8*)(buf + 8192 + rb * 128 + ((q * 16) ^ swb));
      bl[i] = *(const h16x8*)(buf + 8192 + rb * 128 + ((q * 16 + 64) ^ swb));
    }
#pragma unroll
    for (int i = 0; i < 4; ++i)
#pragma unroll
      for (int j = 0; j < 4; ++j)
        acc_hh[i][j] = __builtin_amdgcn_mfma_f32_16x16x32_f16(ah[i], bh[j], acc_hh[i][j], 0, 0, 0);
#pragma unroll
    for (int i = 0; i < 4; ++i)
#pragma unroll
      for (int j = 0; j < 4; ++j)
        acc_mx[i][j] = __builtin_amdgcn_mfma_f32_16x16x32_f16(ah[i], bl[j], acc_mx[i][j], 0, 0, 0);
#pragma unroll
    for (int i = 0; i < 4; ++i)
#pragma unroll
      for (int j = 0; j < 4; ++j)
        acc_mx[i][j] = __builtin_amdgcn_mfma_f32_16x16x32_f16(al[i], bh[j], acc_mx[i][j], 0, 0, 0);

    WAITL0();                                      // our ds_reads of buf done
    SB();
    __builtin_amdgcn_s_barrier();                  // all waves done with buf
    SB();
    if (t <= 12) {
      WAITV(10);                                   // A(t+2) landed
      awrite(areg[(t + 2) & 1], lds + (t & 1) * 40960);
      bgld(lds + (t & 1) * 40960, t + 2);
    } else if (t == 13) {
      WAITV(8);                                    // A15 landed (B14 flies)
      awrite(areg[1], lds + 40960);
      bgld(lds + 40960, 15);
    }
  }

  // ---- epilogue: relu+split -> u32 pack in LDS [64][256], coalesced out --
#pragma unroll
  for (int j = 0; j < 4; ++j) {
    int lcol = wn * 64 + j * 16 + rlo;
    float bv = bias[bn * 256 + lcol];
#pragma unroll
    for (int i = 0; i < 4; ++i)
#pragma unroll
      for (int r = 0; r < 4; ++r) {
        int lrow = i * 16 + q * 4 + r;
        float v = fmaxf(acc_hh[i][j][r] + acc_mx[i][j][r] * LO_INV + bv, 0.0f);
        h16 h = (h16)v;
        h16 l = (h16)((v - (float)h) * LO_SCALE);
        unsigned uu = (unsigned)__builtin_bit_cast(unsigned short, h) |
                      ((unsigned)__builtin_bit_cast(unsigned short, l) << 16);
        *(unsigned*)(lds + lrow * 1024 + lcol * 4) = uu;
      }
  }
  __syncthreads();
#pragma unroll
  for (int pass = 0; pass < 16; ++pass) {
    int o = pass * 4096 + tid * 16;
    int lrow = o >> 10;                            // 1024-B packed rows
    int lcb = o & 1023;
    uint4 d = *(const uint4*)(lds + o);
    uint2 hi, lo;
    hi.x = (d.x & 0xffffu) | (d.y << 16);
    hi.y = (d.z & 0xffffu) | (d.w << 16);
    lo.x = (d.x >> 16) | (d.y & 0xffff0000u);
    lo.y = (d.z >> 16) | (d.w & 0xffff0000u);
    long gb = (arow0 + lrow) * 1024 + bn * 512 + (lcb >> 1);
    *(uint2*)((char*)OHi + gb) = hi;
    *(uint2*)((char*)OLo + gb) = lo;
  }
}

// ====== K2: gemm4 (presplit planes) — logits, pure GEMM (proven) ======
template <int EPI>
__launch_bounds__(256, 2)
__global__ void gemm4_k(const h16* __restrict__ AHi, const h16* __restrict__ ALo,
                        const h16* __restrict__ BHi, const h16* __restrict__ BLo,
                        const float* __restrict__ bias,
                        float* __restrict__ Cf32,
                        h16* __restrict__ OHi, h16* __restrict__ OLo) {
  __shared__ __align__(16) char lds[65536];
  const int tid = threadIdx.x;
  const int wave = tid >> 6, lane = tid & 63;
  const int wg = (blockIdx.x & 7) * 256 + (blockIdx.x >> 3);
  const int bm = wg >> 2, bn = wg & 3;
  const int wm = wave >> 1, wn = wave & 1;
  const long arow0 = (long)bm * 128;
  const int brow0 = bn * 128;
  const int q = lane >> 4, rlo = lane & 15;

  f32x4 acc_hh[4][4] = {};
  f32x4 acc_mx[4][4] = {};

#define STAGE4(bufoff, kt)                                                    \
  {                                                                           \
    _Pragma("unroll")                                                         \
    for (int pass = 0; pass < 4; ++pass) {                                    \
      int p = pass * 4096 + wave * 1024 + lane * 16;                          \
      int row = p >> 7;                                                       \
      int gs = ((p >> 4) & 7) ^ (row & 7);                                    \
      const char* sp = (gs & 4) ? (const char*)ALo : (const char*)AHi;        \
      long off = (arow0 + row) * 1024 + (kt) * 64 + (gs & 3) * 16;            \
      gload16(sp + off, lds + (bufoff) + pass * 4096 + wave * 1024);          \
    }                                                                         \
    _Pragma("unroll")                                                         \
    for (int pass = 0; pass < 4; ++pass) {                                    \
      int p = pass * 4096 + wave * 1024 + lane * 16;                          \
      int row = p >> 7;                                                       \
      int gs = ((p >> 4) & 7) ^ (row & 7);                                    \
      const char* sp = (gs & 4) ? (const char*)BLo : (const char*)BHi;        \
      long off = (long)(brow0 + row) * 1024 + (kt) * 64 + (gs & 3) * 16;      \
      gload16(sp + off, lds + (bufoff) + 16384 + pass * 4096 + wave * 1024);  \
    }                                                                         \
  }

  STAGE4(0, 0);
  STAGE4(32768, 1);

#pragma unroll
  for (int t = 0; t < 16; ++t) {
    if (t < 15) { WAITV(8); } else { WAITV(0); }
    SB();
    __builtin_amdgcn_s_barrier();
    SB();

    const char* buf = lds + (t & 1) * 32768;
    h16x8 ah[4], al[4], bh[4], bl[4];
#pragma unroll
    for (int i = 0; i < 4; ++i) {
      int row = wm * 64 + i * 16 + rlo;
      int sw = (row & 7) << 4;
      ah[i] = *(const h16x8*)(buf + row * 128 + ((q * 16) ^ sw));
      al[i] = *(const h16x8*)(buf + row * 128 + ((q * 16 + 64) ^ sw));
      int rb = wn * 64 + i * 16 + rlo;
      int swb = (rb & 7) << 4;
      bh[i] = *(const h16x8*)(buf + 16384 + rb * 128 + ((q * 16) ^ swb));
      bl[i] = *(const h16x8*)(buf + 16384 + rb * 128 + ((q * 16 + 64) ^ swb));
    }
#pragma unroll
    for (int i = 0; i < 4; ++i)
#pragma unroll
      for (int j = 0; j < 4; ++j)
        acc_hh[i][j] = __builtin_amdgcn_mfma_f32_16x16x32_f16(ah[i], bh[j], acc_hh[i][j], 0, 0, 0);
#pragma unroll
    for (int i = 0; i < 4; ++i)
#pragma unroll
      for (int j = 0; j < 4; ++j)
        acc_mx[i][j] = __builtin_amdgcn_mfma_f32_16x16x32_f16(ah[i], bl[j], acc_mx[i][j], 0, 0, 0);
#pragma unroll
    for (int i = 0; i < 4; ++i)
#pragma unroll
      for (int j = 0; j < 4; ++j)
        acc_mx[i][j] = __builtin_amdgcn_mfma_f32_16x16x32_f16(al[i], bh[j], acc_mx[i][j], 0, 0, 0);

    WAITL0();
    SB();
    __builtin_amdgcn_s_barrier();
    SB();
    if (t + 2 < 16) STAGE4((t & 1) * 32768, t + 2);
  }
#undef STAGE4

#pragma unroll
  for (int j = 0; j < 4; ++j) {
    int lcol = wn * 64 + j * 16 + rlo;
    float bv = bias[bn * 128 + lcol];
#pragma unroll
    for (int i = 0; i < 4; ++i)
#pragma unroll
      for (int r = 0; r < 4; ++r) {
        int lrow = wm * 64 + i * 16 + q * 4 + r;
        float v = acc_hh[i][j][r] + acc_mx[i][j][r] * LO_INV + bv;
        if (EPI == 0) {
          v = fmaxf(v, 0.0f);
          h16 h = (h16)v;
          h16 l = (h16)((v - (float)h) * LO_SCALE);
          unsigned uu = (unsigned)__builtin_bit_cast(unsigned short, h) |
                        ((unsigned)__builtin_bit_cast(unsigned short, l) << 16);
          *(unsigned*)(lds + lrow * 512 + lcol * 4) = uu;
        } else {
          *(float*)(lds + lrow * 512 + lcol * 4) = v;
        }
      }
  }
  __syncthreads();
#pragma unroll
  for (int pass = 0; pass < 16; ++pass) {
    int o = pass * 4096 + tid * 16;
    int lrow = o >> 9;
    int lcb = o & 511;
    if (EPI == 0) {
      uint4 d = *(const uint4*)(lds + o);
      uint2 hi, lo;
      hi.x = (d.x & 0xffffu) | (d.y << 16);
      hi.y = (d.z & 0xffffu) | (d.w << 16);
      lo.x = (d.x >> 16) | (d.y & 0xffff0000u);
      lo.y = (d.z >> 16) | (d.w & 0xffff0000u);
      long gb = (arow0 + lrow) * 1024 + bn * 256 + (lcb >> 1);
      *(uint2*)((char*)OHi + gb) = hi;
      *(uint2*)((char*)OLo + gb) = lo;
    } else {
      f32x4 d = *(const f32x4*)(lds + o);
      long gb = (arow0 + lrow) * 2048 + bn * 512 + lcb;
      *(f32x4*)((char*)Cf32 + gb) = d;
    }
  }
}

// ---------------- K3: gumbel + argmax + codebook gather ----------------
__global__ void k3_argmax_gather(const float* __restrict__ logits,
                                 const float* __restrict__ u,
                                 const float* __restrict__ cb,
                                 const int* __restrict__ testing,
                                 float* __restrict__ codes) {
  const int wave = threadIdx.x >> 6, lane = threadIdx.x & 63;
  const long row = (long)blockIdx.x * 4 + wave;    // one wave per row
  const f32x4* lrow = (const f32x4*)(logits + row * 512);
  const f32x4* urow = (const f32x4*)(u + row * 512);
  const int test = *testing;

  float best = -3.4e38f;
  int bi = 0;
#pragma unroll
  for (int h = 0; h < 2; ++h) {
    int c4 = h * 64 + lane;
    f32x4 z = lrow[c4];
    if (!test) {
      f32x4 uu = urow[c4];
#pragma unroll
      for (int t = 0; t < 4; ++t)
        z[t] += -logf(-logf(uu[t] + 1e-20f) + 1e-20f);
    }
#pragma unroll
    for (int t = 0; t < 4; ++t) {                  // in-lane ascending indices
      int c = c4 * 4 + t;
      if (z[t] > best) { best = z[t]; bi = c; }
    }
  }
#pragma unroll
  for (int off = 32; off; off >>= 1) {             // max with min-index ties
    float ob = __shfl_xor(best, off);
    int oi = __shfl_xor(bi, off);
    if (ob > best || (ob == best && oi < bi)) { best = ob; bi = oi; }
  }
  const f32x4* src = (const f32x4*)(cb + (long)bi * 512);
  f32x4* dst = (f32x4*)(codes + row * 512);
  dst[lane] = src[lane];
  dst[lane + 64] = src[lane + 64];
}

// ---------------- host ----------------
extern "C" void kernel_launch(void* const* d_in, const int* in_sizes, int n_in,
                              void* d_out, int out_size, void* d_ws, size_t ws_size,
                              hipStream_t stream) {
  const float* X = (const float*)d_in[0];
  const float* Wh = (const float*)d_in[1];
  const float* bh = (const float*)d_in[2];
  const float* Wl = (const float*)d_in[3];
  const float* bl = (const float*)d_in[4];
  const float* cb = (const float*)d_in[5];
  const float* u = (const float*)d_in[6];
  const int* testing = (const int*)d_in[7];

  float* logits = (float*)d_out;                   // 33554432 f32
  float* codes = logits + 33554432;                // 33554432 f32
  // hiddens hi/lo f16 planes live in the codes region until K3 overwrites it
  h16* Hhi = (h16*)codes;
  h16* Hlo = Hhi + 33554432;

  h16* WhHi = (h16*)d_ws;                          // 4 x 0.5 MB weight planes
  h16* WhLo = WhHi + 262144;
  h16* WlHi = WhLo + 262144;
  h16* WlLo = WlHi + 262144;

  split_w<<<dim3(1024), dim3(256), 0, stream>>>(Wh, Wl, WhHi, WhLo, WlHi, WlLo);

  gemm7_k<<<dim3(2048), dim3(256), 0, stream>>>(X, WhHi, WhLo, bh, Hhi, Hlo);

  gemm4_k<1><<<dim3(2048), dim3(256), 0, stream>>>(Hhi, Hlo, WlHi, WlLo, bl,
                                                   logits, nullptr, nullptr);

  k3_argmax_gather<<<dim3(16384), dim3(256), 0, stream>>>(logits, u, cb, testing, codes);
}